// Round 13
// baseline (43.855 us; speedup 1.0000x reference)
//
#include <hip/hip_runtime.h>
#include <math.h>

#define C_CH 256
#define KTOP 26
#define HWSZ 3136            // 56*56
#define NPIX 100352          // 32*3136
#define CHW  (C_CH * HWSZ)
#define PIX_PER_BLK 64
#define BLKS_PER_IMG 49      // 3136 / 64

typedef float f32x4 __attribute__((ext_vector_type(4)));

__device__ __forceinline__ void ce_desc(float& a, float& b) {
    float mx = fmaxf(a, b); float mn = fminf(a, b); a = mx; b = mn;
}
__device__ __forceinline__ void ce_asc(float& a, float& b) {
    float mn = fminf(a, b); float mx = fmaxf(a, b); a = mn; b = mx;
}

// Full bitonic sort of 32 values -> descending. 240 CE, static indices.
__device__ __forceinline__ void sort32_desc(float* v) {
#pragma unroll
    for (int k = 2; k <= 32; k <<= 1) {
#pragma unroll
        for (int j = k >> 1; j > 0; j >>= 1) {
#pragma unroll
            for (int i = 0; i < 32; ++i) {
                int l = i ^ j;
                if (l > i) {
                    if ((i & k) == 0) ce_desc(v[i], v[l]);
                    else              ce_asc(v[i], v[l]);
                }
            }
        }
    }
}

// Clean an already-bitonic 32 sequence -> descending. 80 CE.
__device__ __forceinline__ void clean32_desc(float* v) {
#pragma unroll
    for (int j = 16; j > 0; j >>= 1) {
#pragma unroll
        for (int i = 0; i < 32; ++i) {
            int l = i ^ j;
            if (l > i) ce_desc(v[i], v[l]);
        }
    }
}

// Merge own desc-26 (a[0..25]) with LDS desc-26 list -> a = sorted top-26 of
// union. [a pad32 desc | rev(src) pad32 asc] is bitonic-64; max-half keeps
// ranks 0..31 (bitonic), clean -> sorted desc. (verified R2-R12)
__device__ __forceinline__ void merge26(float* a, const float* __restrict__ src) {
    float h[32];
#pragma unroll
    for (int i = 0; i < 32; ++i) {
        float u = (i < KTOP)      ? a[i]        : -INFINITY;
        float w = (31 - i < KTOP) ? src[31 - i] : -INFINITY;
        h[i] = fmaxf(u, w);
    }
    clean32_desc(h);
#pragma unroll
    for (int j = 0; j < KTOP; ++j) a[j] = h[j];
}

__global__ __launch_bounds__(512, 4) void kwinners_kernel(
    const float* __restrict__ x, const float* __restrict__ duty,
    const float* __restrict__ bsp, float* __restrict__ out)
{
    __shared__ float s[C_CH];
    __shared__ float tile[C_CH][PIX_PER_BLK];  // 64 KB, quad-rotated columns
    __shared__ float pub[4][32][KTOP];         // 13 KB
    __shared__ float thr_s[PIX_PER_BLK];
    // Total LDS = 1024 + 65536 + 13312 + 256 = 80128 B -> 2 blocks/CU.

    const int t   = threadIdx.x;
    const int w   = t >> 6;                 // wave id (0..7)
    const int l   = t & 63;                 // lane
    const int blk = blockIdx.x;
    const int b   = blk / BLKS_PER_IMG;
    const int hw0 = (blk - b * BLKS_PER_IMG) * PIX_PER_BLK;

    // ---- Stage: wave w loads rows [32w, 32w+32). Per instr: 64 lanes x 16B
    // = 4 rows x 256 B, LDS dest linear (base + lane*16, HW rule). Column
    // rotation swizzle applied on the GLOBAL source: physical quad p of row R
    // holds logical quad (p - R) & 15.
    {
        const int p    = l & 15;            // physical quad this lane fills
        const int rsub = l >> 4;            // row within 4-row group
#pragma unroll
        for (int it = 0; it < 8; ++it) {
            const int Rb = w * 32 + it * 4;
            const int R  = Rb + rsub;
            const int lq = (p - R) & 15;    // logical quad to fetch
            const float* gp = x + (size_t)b * CHW + (size_t)R * HWSZ
                                + hw0 + lq * 4;
            __builtin_amdgcn_global_load_lds(
                (const __attribute__((address_space(1))) void*)gp,
                (__attribute__((address_space(3))) void*)&tile[Rb][0],
                16, 0, 0);
        }
    }

    // exp table while loads fly. scale = exp(-bs*duty[c]); fp32 mul, exp in
    // double rounded to fp32 -> correctly-rounded. (absmax=0, R1-R12)
    if (t < C_CH) {
        float bs = bsp[0];
        float m = -(bs * duty[t]);
        s[t] = (float)exp((double)m);
    }
    __syncthreads();   // drains vmcnt (stage is cross-wave-consumed here)

    const int qc = w >> 1;                  // channel quarter (0..3)
    const int ph = w & 1;                   // pixel half (0..1)
    const int hf = l >> 5;                  // lane half = 32-ch subgroup
    const int pl = l & 31;
    const int px = ph * 32 + pl;            // logical pixel (0..63)
    const int c0 = qc * 64 + hf * 32;       // first channel of this lane

    // ---- Boost own 32 channels from LDS (rotation-swizzled cols), sort ----
    float v[32];
    {
        int col = ((((px >> 2) + c0) & 15) << 2) | (px & 3);
#pragma unroll
        for (int i = 0; i < 32; ++i) {
            v[i] = tile[c0 + i][col] * s[c0 + i];
            col = (col + 4) & 63;           // quad rotates by 1 per row
        }
    }
    sort32_desc(v);

    // ---- L1 (intra-wave): merge with partner half via shfl_xor(32) ----
    float a[KTOP];
    {
        float h[32];
#pragma unroll
        for (int i = 0; i < 32; ++i)
            h[i] = fmaxf(v[i], __shfl_xor(v[31 - i], 32));
        clean32_desc(h);
#pragma unroll
        for (int j = 0; j < KTOP; ++j) a[j] = h[j];
    }
    // a = sorted top-26 of channels [64qc, 64qc+64), identical in both halves.

    // ---- Publish for L2: w2->pub0, w3->pub1, w6->pub2, w7->pub3 ----
    if ((w == 2 || w == 3 || w == 6 || w == 7) && hf == 0) {
        float* dst = pub[(w < 4) ? (w - 2) : (w - 4)][pl];
#pragma unroll
        for (int j = 0; j < KTOP; ++j) dst[j] = a[j];
    }
    __syncthreads();

    // ---- L2: w0<-p0, w1<-p1, w4<-p2, w5<-p3; w4/w5 republish for L3 ----
    if (w == 0) {
        merge26(a, pub[0][pl]);             // ch 0..127, ph0
    } else if (w == 1) {
        merge26(a, pub[1][pl]);             // ch 0..127, ph1
    } else if (w == 4) {
        merge26(a, pub[2][pl]);             // ch 128..255, ph0
        if (hf == 0) {
            float* dst = pub[2][pl];        // own source, reads done (in-wave)
#pragma unroll
            for (int j = 0; j < KTOP; ++j) dst[j] = a[j];
        }
    } else if (w == 5) {
        merge26(a, pub[3][pl]);             // ch 128..255, ph1
        if (hf == 0) {
            float* dst = pub[3][pl];
#pragma unroll
            for (int j = 0; j < KTOP; ++j) dst[j] = a[j];
        }
    }
    __syncthreads();

    // ---- L3 (w0: ph0, w1: ph1): merge + rank-25 cascade -> thr ----
    if (w <= 1) {
        const float* src = pub[2 + w][pl];
        float h[32];
#pragma unroll
        for (int i = 0; i < 32; ++i) {
            float u  = (i < KTOP)      ? a[i]        : -INFINITY;
            float wv = (31 - i < KTOP) ? src[31 - i] : -INFINITY;
            h[i] = fmaxf(u, wv);                      // ranks 0..31 of 256, r=25
        }
        float l16[16];
#pragma unroll
        for (int i = 0; i < 16; ++i) l16[i] = fminf(h[i], h[i + 16]);    // r=9
        float l8[8];
#pragma unroll
        for (int i = 0; i < 8; ++i)  l8[i]  = fminf(l16[i], l16[i + 8]); // r=1
        float h4[4];
#pragma unroll
        for (int i = 0; i < 4; ++i)  h4[i]  = fmaxf(l8[i], l8[i + 4]);   // r=1
        float h2[2];
#pragma unroll
        for (int i = 0; i < 2; ++i)  h2[i]  = fmaxf(h4[i], h4[i + 2]);   // r=1
        if (hf == 0) thr_s[w * 32 + pl] = fminf(h2[0], h2[1]);
    }
    __syncthreads();

    // ---- Write: wave w covers its staged rows [32w,32w+32). Lane ->
    // (r4 = l>>4, logical quad pg = l&15): 16 lanes/row = 256 B contiguous.
    {
        const int pg = l & 15;
        const int r4 = l >> 4;
        const float t0 = thr_s[pg * 4 + 0];
        const float t1 = thr_s[pg * 4 + 1];
        const float t2 = thr_s[pg * 4 + 2];
        const float t3 = thr_s[pg * 4 + 3];
#pragma unroll
        for (int it = 0; it < 8; ++it) {
            const int row = w * 32 + it * 4 + r4;
            const int pq  = (pg + row) & 15;           // physical quad
            const f32x4 xv = *reinterpret_cast<const f32x4*>(&tile[row][pq * 4]);
            const float scv = s[row];
            f32x4 res;
            res.x = (xv.x * scv >= t0) ? xv.x : 0.0f;
            res.y = (xv.y * scv >= t1) ? xv.y : 0.0f;
            res.z = (xv.z * scv >= t2) ? xv.z : 0.0f;
            res.w = (xv.w * scv >= t3) ? xv.w : 0.0f;
            __builtin_nontemporal_store(
                res, reinterpret_cast<f32x4*>(
                    out + (size_t)b * CHW + (size_t)row * HWSZ + hw0 + pg * 4));
        }
    }
}

extern "C" void kernel_launch(void* const* d_in, const int* in_sizes, int n_in,
                              void* d_out, int out_size, void* d_ws, size_t ws_size,
                              hipStream_t stream) {
    const float* x    = (const float*)d_in[0];
    const float* duty = (const float*)d_in[1];
    // d_in[2] = k (int, ==26 hardcoded), d_in[3] = boost_strength (float)
    const float* bs   = (const float*)d_in[3];
    float* out = (float*)d_out;

    hipLaunchKernelGGL(kwinners_kernel, dim3(NPIX / PIX_PER_BLK), dim3(512), 0,
                       stream, x, duty, bs, out);
}